// Round 9
// baseline (318.300 us; speedup 1.0000x reference)
//
#include <hip/hip_runtime.h>

#define N_NODES 50000
#define N_EDGES 640000
#define F 128
#define DFF 512
#define NB 196   // ceil(N_NODES/256)

using u32 = unsigned int;
using u16 = unsigned short;

typedef __bf16 bf16x8 __attribute__((ext_vector_type(8)));
typedef float f32x4 __attribute__((ext_vector_type(4)));

__device__ __forceinline__ float bf2f(u16 u) {
    return __uint_as_float(((u32)u) << 16);
}
__device__ __forceinline__ float blo(u32 p) { return __uint_as_float(p << 16); }
__device__ __forceinline__ float bhi(u32 p) { return __uint_as_float(p & 0xffff0000u); }
__device__ __forceinline__ u16 f2bf(float f) {
    u32 u = __float_as_uint(f);
    u += 0x7fffu + ((u >> 16) & 1u);   // RNE
    return (u16)(u >> 16);
}
__device__ __forceinline__ u32 pack2(float a, float b) {
    return (u32)f2bf(a) | ((u32)f2bf(b) << 16);
}

// ---------------- CSR build ----------------
__global__ void k_hist(const int* __restrict__ dst, int* __restrict__ cnt) {
    int e = blockIdx.x * 256 + threadIdx.x;
    if (e < N_EDGES) atomicAdd(&cnt[dst[e]], 1);
}

__global__ void k_bsum(const int* __restrict__ counts, int* __restrict__ bsum) {
    int i = blockIdx.x * 256 + threadIdx.x;
    int v = (i < N_NODES) ? counts[i] : 0;
#pragma unroll
    for (int off = 32; off >= 1; off >>= 1) v += __shfl_xor(v, off, 64);
    __shared__ int ws[4];
    int lane = threadIdx.x & 63, wid = threadIdx.x >> 6;
    if (lane == 0) ws[wid] = v;
    __syncthreads();
    if (threadIdx.x == 0) bsum[blockIdx.x] = ws[0] + ws[1] + ws[2] + ws[3];
}

// self-scanning bfill: block b sums bsum[0..b) itself, then in-block exclusive scan
__global__ void k_bfill(const int* __restrict__ counts, const int* __restrict__ bsum,
                        int* __restrict__ row_ptr) {
    const int b = blockIdx.x, t = threadIdx.x;
    const int lane = t & 63, wid = t >> 6;
    __shared__ int wsum[4];
    __shared__ int ws[4];

    // block offset = sum of bsum[j] for j < b   (b <= 195 < 256)
    int bv = (t < b) ? bsum[t] : 0;
#pragma unroll
    for (int off = 32; off >= 1; off >>= 1) bv += __shfl_xor(bv, off, 64);
    if (lane == 0) wsum[wid] = bv;
    __syncthreads();
    const int boff = wsum[0] + wsum[1] + wsum[2] + wsum[3];

    // in-block exclusive scan of counts
    int i = b * 256 + t;
    int v = (i < N_NODES) ? counts[i] : 0;
    int incl = v;
#pragma unroll
    for (int off = 1; off < 64; off <<= 1) {
        int u = __shfl_up(incl, off, 64);
        if (lane >= off) incl += u;
    }
    if (lane == 63) ws[wid] = incl;
    __syncthreads();
    int wo = 0;
#pragma unroll
    for (int j = 0; j < 4; ++j) if (j < wid) wo += ws[j];
    if (i < N_NODES) row_ptr[i] = boff + wo + incl - v;
    if (i == 0) row_ptr[N_NODES] = N_EDGES;
}

// consumes counts via atomicSub: pos = row_ptr[d+1] - remaining
__global__ void k_fill(const int* __restrict__ src, const int* __restrict__ dst,
                       const int* __restrict__ row_ptr, int* __restrict__ counts,
                       int* __restrict__ csr_src) {
    int e = blockIdx.x * 256 + threadIdx.x;
    if (e < N_EDGES) {
        int d = dst[e];
        int old = atomicSub(&counts[d], 1);
        csr_src[row_ptr[d + 1] - old] = src[e];
    }
}

// ---------------- prep: feat fp32->bf16 + 5 weights -> bf16 transposed + zero counts ----
#define FEAT_UNITS (N_NODES * F / 4)   // 1,600,000 float4 units
#define CNT_UNITS  ((N_NODES + 3) / 4) // 12,500 int4 units
__global__ void k_prep(const float* __restrict__ feat, u16* __restrict__ featb,
                       const float* __restrict__ Wq, const float* __restrict__ Wk,
                       const float* __restrict__ Wv, const float* __restrict__ W1,
                       const float* __restrict__ W2, u16* __restrict__ WT,
                       int* __restrict__ counts) {
    int idx = blockIdx.x * 256 + threadIdx.x;
    if (idx < FEAT_UNITS) {
        float4 v = reinterpret_cast<const float4*>(feat)[idx];
        uint2 p;
        p.x = pack2(v.x, v.y);
        p.y = pack2(v.z, v.w);
        reinterpret_cast<uint2*>(featb)[idx] = p;
        return;
    }
    int wi = idx - FEAT_UNITS;
    if (wi < 49152) {
        int mi = wi >> 14;
        int local = wi & 16383;
        const float* W = (mi == 0) ? Wq : ((mi == 1) ? Wk : Wv);
        int n = local >> 7, k = local & 127;
        WT[wi] = f2bf(W[(size_t)k * 128 + n]);
    } else if (wi < 114688) {
        int local = wi - 49152;
        int n = local >> 7, k = local & 127;
        WT[wi] = f2bf(W1[(size_t)k * 512 + n]);
    } else if (wi < 180224) {
        int local = wi - 114688;
        int n = local >> 9, k = local & 511;
        WT[wi] = f2bf(W2[(size_t)k * 128 + n]);
    } else if (wi < 180224 + CNT_UNITS) {
        reinterpret_cast<int4*>(counts)[wi - 180224] = make_int4(0, 0, 0, 0);
    }
}

// ---------------- MFMA GEMM: 128x128 tile, K-chunk 64 reg-dbuf, XOR-swizzled LDS ----------
// LDS tile layout: row r (64 u16 = 8 granules of 16B), granule i stored at
//   byte (r*8 + (i ^ (r&7))) * 16  -> staging writes conflict-free, frag reads 2-way (free)
// frag mapping: row = row0 + w*32 + mt*16 + q4*4 + j ; col = cb + nt*16 + ln
// EPI 0: bf16 store via LDS-staged coalesced uint4 (qkv)
// EPI 1: +bias, PReLU, bf16 store via LDS-staged coalesced uint4 (ffn1 -> h)
// EPI 2: +bias +resid(bf16), row LayerNorm, fp32 store (ffn2 -> out)
template <int EPI>
__global__ __launch_bounds__(256) void k_mm(
    const u16* __restrict__ A, int lda,
    const u16* __restrict__ BT,
    void* __restrict__ Cv, int ldc,
    int K,
    const float* __restrict__ bias,
    const float* __restrict__ prelu,
    const u16* __restrict__ resid,
    const float* __restrict__ g,
    const float* __restrict__ bb)
{
    // staging needs 2*128*64 u16 = 16384; EPI0/1 C-staging needs 128*136 = 17408
    __shared__ u16 smem[17408];
    u16* sA = smem;                 // 128 rows x 64 u16 (swizzled)
    u16* sB = smem + 128 * 64;
    u16* sC = smem;                 // epilogue overlay

    const int t = threadIdx.x;
    const int w = t >> 6;
    const int lane = t & 63;
    const int ln = lane & 15, q4 = lane >> 4;
    const int row0 = blockIdx.x * 128;
    const int cb = blockIdx.y * 128;

    f32x4 acc[2][8];
#pragma unroll
    for (int mt = 0; mt < 2; ++mt)
#pragma unroll
        for (int nt = 0; nt < 8; ++nt)
            acc[mt][nt] = (f32x4){0.f, 0.f, 0.f, 0.f};

    uint4 pa[4], pb[4];
#define LOAD_A(kc)                                                             \
    {                                                                          \
        _Pragma("unroll") for (int i = 0; i < 4; ++i) {                        \
            int u = i * 256 + t, r = u >> 3, k8 = (u & 7) * 8;                 \
            int row = row0 + r;                                                \
            uint4 val = make_uint4(0, 0, 0, 0);                                \
            if (row < N_NODES)                                                 \
                val = *reinterpret_cast<const uint4*>(A + (size_t)row * lda + (kc) + k8); \
            pa[i] = val;                                                       \
        }                                                                      \
    }
#define LOAD_B(kc)                                                             \
    {                                                                          \
        _Pragma("unroll") for (int i = 0; i < 4; ++i) {                        \
            int u = i * 256 + t, r = u >> 3, k8 = (u & 7) * 8;                 \
            pb[i] = *reinterpret_cast<const uint4*>(BT + (size_t)(cb + r) * K + (kc) + k8); \
        }                                                                      \
    }

    LOAD_A(0);
    LOAD_B(0);

    for (int kc = 0; kc < K; kc += 64) {
#pragma unroll
        for (int i = 0; i < 4; ++i) {
            int u = i * 256 + t, r = u >> 3, gi = u & 7;
            int off = (r * 8 + (gi ^ (r & 7))) * 8;
            *reinterpret_cast<uint4*>(&sA[off]) = pa[i];
            *reinterpret_cast<uint4*>(&sB[off]) = pb[i];
        }
        __syncthreads();
        if (kc + 64 < K) {
            LOAD_A(kc + 64);
            LOAD_B(kc + 64);
        }
#pragma unroll
        for (int ks = 0; ks < 2; ++ks) {
            const int gsw = ks * 4 + q4;
            const int rA0 = w * 32 + ln;
            const int rA1 = rA0 + 16;
            bf16x8 a0 = *reinterpret_cast<const bf16x8*>(&sA[(rA0 * 8 + (gsw ^ (rA0 & 7))) * 8]);
            bf16x8 a1 = *reinterpret_cast<const bf16x8*>(&sA[(rA1 * 8 + (gsw ^ (rA1 & 7))) * 8]);
#pragma unroll
            for (int nt = 0; nt < 8; ++nt) {
                const int rB = nt * 16 + ln;
                bf16x8 b = *reinterpret_cast<const bf16x8*>(&sB[(rB * 8 + (gsw ^ (rB & 7))) * 8]);
                acc[0][nt] = __builtin_amdgcn_mfma_f32_16x16x32_bf16(a0, b, acc[0][nt], 0, 0, 0);
                acc[1][nt] = __builtin_amdgcn_mfma_f32_16x16x32_bf16(a1, b, acc[1][nt], 0, 0, 0);
            }
        }
        __syncthreads();
    }
#undef LOAD_A
#undef LOAD_B

    if (EPI == 0 || EPI == 1) {
        // bias/prelu (EPI1) on frags, stage to LDS, coalesced uint4 stores
        float bs[8], pr[8];
        if (EPI == 1) {
#pragma unroll
            for (int nt = 0; nt < 8; ++nt) {
                int col = cb + nt * 16 + ln;
                bs[nt] = bias[col];
                pr[nt] = prelu[col];
            }
        }
#pragma unroll
        for (int mt = 0; mt < 2; ++mt)
#pragma unroll
            for (int nt = 0; nt < 8; ++nt)
#pragma unroll
                for (int j = 0; j < 4; ++j) {
                    float x = acc[mt][nt][j];
                    if (EPI == 1) {
                        x += bs[nt];
                        x = (x >= 0.f) ? x : pr[nt] * x;
                    }
                    sC[(w * 32 + mt * 16 + q4 * 4 + j) * 136 + nt * 16 + ln] = f2bf(x);
                }
        __syncthreads();
        u16* C = (u16*)Cv;
#pragma unroll
        for (int i = 0; i < 8; ++i) {
            int u = i * 256 + t;
            int r = u >> 4, c8 = (u & 15) * 8;
            int row = row0 + r;
            if (row < N_NODES) {
                uint4 val = *reinterpret_cast<const uint4*>(&sC[r * 136 + c8]);
                *reinterpret_cast<uint4*>(&C[(size_t)row * ldc + cb + c8]) = val;
            }
        }
    } else {
        // bias + resid(bf16) + row LayerNorm, fp32 out. Block covers all 128 cols (cb==0).
        float* C = (float*)Cv;
        float bs[8], gv[8], bv[8];
#pragma unroll
        for (int nt = 0; nt < 8; ++nt) {
            int col = nt * 16 + ln;
            bs[nt] = bias[col];
            gv[nt] = g[col];
            bv[nt] = bb[col];
        }
#pragma unroll
        for (int mt = 0; mt < 2; ++mt)
#pragma unroll
            for (int j = 0; j < 4; ++j) {
                int row = row0 + w * 32 + mt * 16 + q4 * 4 + j;
                bool ok = row < N_NODES;
                float vals[8];
                float s = 0.f, ss = 0.f;
#pragma unroll
                for (int nt = 0; nt < 8; ++nt) {
                    float x = acc[mt][nt][j] + bs[nt];
                    if (ok) x += bf2f(resid[(size_t)row * 128 + nt * 16 + ln]);
                    vals[nt] = x;
                    s += x; ss += x * x;
                }
                s += __shfl_xor(s, 8, 16); ss += __shfl_xor(ss, 8, 16);
                s += __shfl_xor(s, 4, 16); ss += __shfl_xor(ss, 4, 16);
                s += __shfl_xor(s, 2, 16); ss += __shfl_xor(ss, 2, 16);
                s += __shfl_xor(s, 1, 16); ss += __shfl_xor(ss, 1, 16);
                float mu = s * (1.f / 128.f);
                float var = ss * (1.f / 128.f) - mu * mu;
                float rs = rsqrtf(var + 1e-5f);
                if (ok) {
#pragma unroll
                    for (int nt = 0; nt < 8; ++nt)
                        C[(size_t)row * 128 + nt * 16 + ln] =
                            (vals[nt] - mu) * rs * gv[nt] + bv[nt];
                }
            }
    }
}

// ---------------- attention: 1 wave/node, 2 dims/lane, no-max softmax, unroll-4 ----------
// qkv per node (u32 view, 192 words): q words 0..63, k words 64..127, v words 128..191
__global__ __launch_bounds__(256) void k_attn(
    const u32* __restrict__ Q32, const float* __restrict__ feat,
    const int* __restrict__ row_ptr, const int* __restrict__ csr_src,
    const float* __restrict__ g, const float* __restrict__ bb,
    u16* __restrict__ rstb)
{
    const int w = threadIdx.x >> 6;
    const int lane = threadIdx.x & 63;
    const int n = blockIdx.x * 4 + w;
    if (n >= N_NODES) return;
    const float scale = 0.08838834764831845f;  // 1/sqrt(128)

    const u32 qp = Q32[(size_t)n * 192 + lane];
    const float q0 = blo(qp), q1 = bhi(qp);
    const int e0 = row_ptr[n], e1 = row_ptr[n + 1];

    float l = 0.f, a0 = 0.f, a1 = 0.f;
    int e = e0;
    for (; e + 4 <= e1; e += 4) {
        int s0 = csr_src[e], s1 = csr_src[e + 1], s2 = csr_src[e + 2], s3 = csr_src[e + 3];
        u32 kp0 = Q32[(size_t)s0 * 192 + 64 + lane];
        u32 kp1 = Q32[(size_t)s1 * 192 + 64 + lane];
        u32 kp2 = Q32[(size_t)s2 * 192 + 64 + lane];
        u32 kp3 = Q32[(size_t)s3 * 192 + 64 + lane];
        u32 vp0 = Q32[(size_t)s0 * 192 + 128 + lane];
        u32 vp1 = Q32[(size_t)s1 * 192 + 128 + lane];
        u32 vp2 = Q32[(size_t)s2 * 192 + 128 + lane];
        u32 vp3 = Q32[(size_t)s3 * 192 + 128 + lane];
        float p0 = blo(kp0) * q0 + bhi(kp0) * q1;
        float p1 = blo(kp1) * q0 + bhi(kp1) * q1;
        float p2 = blo(kp2) * q0 + bhi(kp2) * q1;
        float p3 = blo(kp3) * q0 + bhi(kp3) * q1;
        p0 += __shfl_xor(p0, 4, 8); p1 += __shfl_xor(p1, 4, 8);
        p2 += __shfl_xor(p2, 4, 8); p3 += __shfl_xor(p3, 4, 8);
        p0 += __shfl_xor(p0, 2, 8); p1 += __shfl_xor(p1, 2, 8);
        p2 += __shfl_xor(p2, 2, 8); p3 += __shfl_xor(p3, 2, 8);
        p0 += __shfl_xor(p0, 1, 8); p1 += __shfl_xor(p1, 1, 8);
        p2 += __shfl_xor(p2, 1, 8); p3 += __shfl_xor(p3, 1, 8);
        float ea = __expf(p0 * scale), eb = __expf(p1 * scale);
        float ec = __expf(p2 * scale), ed = __expf(p3 * scale);
        l += (ea + eb) + (ec + ed);
        a0 += ea * blo(vp0) + eb * blo(vp1) + ec * blo(vp2) + ed * blo(vp3);
        a1 += ea * bhi(vp0) + eb * bhi(vp1) + ec * bhi(vp2) + ed * bhi(vp3);
    }
    for (; e < e1; ++e) {
        int s0 = csr_src[e];
        u32 kp0 = Q32[(size_t)s0 * 192 + 64 + lane];
        u32 vp0 = Q32[(size_t)s0 * 192 + 128 + lane];
        float p0 = blo(kp0) * q0 + bhi(kp0) * q1;
        p0 += __shfl_xor(p0, 4, 8);
        p0 += __shfl_xor(p0, 2, 8);
        p0 += __shfl_xor(p0, 1, 8);
        float ea = __expf(p0 * scale);
        l += ea;
        a0 += ea * blo(vp0);
        a1 += ea * bhi(vp0);
    }
    float inv = (l > 0.f) ? 1.f / l : 0.f;   // deg-0 node -> 0
    const int c2 = lane * 2;
    const float2 fr = *reinterpret_cast<const float2*>(feat + (size_t)n * 128 + c2);
    float x0 = a0 * inv + fr.x;
    float x1 = a1 * inv + fr.y;

    float sum = x0 + x1, sq = x0 * x0 + x1 * x1;
#pragma unroll
    for (int off = 32; off >= 1; off >>= 1) {
        sum += __shfl_xor(sum, off, 64);
        sq += __shfl_xor(sq, off, 64);
    }
    float mu = sum * (1.f / 128.f);
    float var = sq * (1.f / 128.f) - mu * mu;
    float rs = rsqrtf(var + 1e-5f);
    float y0 = (x0 - mu) * rs * g[c2] + bb[c2];
    float y1 = (x1 - mu) * rs * g[c2 + 1] + bb[c2 + 1];
    reinterpret_cast<u32*>(rstb)[(size_t)n * 64 + lane] = pack2(y0, y1);
}

extern "C" void kernel_launch(void* const* d_in, const int* in_sizes, int n_in,
                              void* d_out, int out_size, void* d_ws, size_t ws_size,
                              hipStream_t stream)
{
    const float* feat = (const float*)d_in[0];
    const int* src    = (const int*)d_in[1];
    const int* dst    = (const int*)d_in[2];
    const float* Wq   = (const float*)d_in[3];
    const float* Wk   = (const float*)d_in[4];
    const float* Wv   = (const float*)d_in[5];
    const float* ln_g = (const float*)d_in[6];
    const float* ln_b = (const float*)d_in[7];
    const float* W1   = (const float*)d_in[8];
    const float* b1   = (const float*)d_in[9];
    const float* pa   = (const float*)d_in[10];
    const float* W2   = (const float*)d_in[11];
    const float* b2   = (const float*)d_in[12];

    u16* qkv   = (u16*)d_ws;                           // 50000*384
    u16* h     = qkv + (size_t)N_NODES * 384;          // 50000*512 (featb aliases front)
    u16* featb = h;                                    // 50000*128, dead before h written
    u16* rstb  = h + (size_t)N_NODES * 512;            // 50000*128
    u16* WT    = rstb + (size_t)N_NODES * 128;         // 180224
    u16* BqkvT = WT;
    u16* W1T   = WT + 49152;
    u16* W2T   = WT + 114688;
    int* counts  = (int*)(WT + 180224);
    int* row_ptr = counts + ((N_NODES + 3) & ~3);      // keep counts int4-aligned region
    int* csr_src = row_ptr + N_NODES + 1;
    int* bsum    = csr_src + N_EDGES;

    // prep (feat->bf16, weights->bf16^T, zero counts)
    k_prep<<<(FEAT_UNITS + 180224 + CNT_UNITS + 255) / 256, 256, 0, stream>>>(
        feat, featb, Wq, Wk, Wv, W1, W2, WT, counts);

    // CSR: hist -> block sums -> self-scanning bfill -> consuming fill
    k_hist<<<(N_EDGES + 255) / 256, 256, 0, stream>>>(dst, counts);
    k_bsum<<<NB, 256, 0, stream>>>(counts, bsum);
    k_bfill<<<NB, 256, 0, stream>>>(counts, bsum, row_ptr);
    k_fill<<<(N_EDGES + 255) / 256, 256, 0, stream>>>(src, dst, row_ptr, counts, csr_src);

    const int MBK = (N_NODES + 127) / 128;   // 391

    dim3 gqkv(MBK, 3);
    k_mm<0><<<gqkv, 256, 0, stream>>>(featb, 128, BqkvT, qkv, 384, 128,
                                      nullptr, nullptr, nullptr, nullptr, nullptr);

    k_attn<<<(N_NODES + 3) / 4, 256, 0, stream>>>((const u32*)qkv, feat, row_ptr, csr_src,
                                                  ln_g, ln_b, rstb);

    dim3 gf1(MBK, 4);
    k_mm<1><<<gf1, 256, 0, stream>>>(rstb, 128, W1T, h, 512, 128,
                                     b1, pa, nullptr, nullptr, nullptr);

    dim3 gf2(MBK, 1);
    k_mm<2><<<gf2, 256, 0, stream>>>(h, 512, W2T, d_out, 128, 512,
                                     b2, nullptr, rstb, ln_g, ln_b);
}

// Round 10
// 317.953 us; speedup vs baseline: 1.0011x; 1.0011x over previous
//
#include <hip/hip_runtime.h>

#define N_NODES 50000
#define N_EDGES 640000
#define F 128
#define DFF 512
#define NB 196   // ceil(N_NODES/256)

using u32 = unsigned int;
using u16 = unsigned short;

typedef __bf16 bf16x8 __attribute__((ext_vector_type(8)));
typedef float f32x4 __attribute__((ext_vector_type(4)));

__device__ __forceinline__ float bf2f(u16 u) {
    return __uint_as_float(((u32)u) << 16);
}
__device__ __forceinline__ float blo(u32 p) { return __uint_as_float(p << 16); }
__device__ __forceinline__ float bhi(u32 p) { return __uint_as_float(p & 0xffff0000u); }
__device__ __forceinline__ u16 f2bf(float f) {
    u32 u = __float_as_uint(f);
    u += 0x7fffu + ((u >> 16) & 1u);   // RNE
    return (u16)(u >> 16);
}
__device__ __forceinline__ u32 pack2(float a, float b) {
    return (u32)f2bf(a) | ((u32)f2bf(b) << 16);
}

// ---------------- CSR build ----------------
__global__ void k_hist(const int* __restrict__ dst, int* __restrict__ cnt) {
    int e = blockIdx.x * 256 + threadIdx.x;
    if (e < N_EDGES) atomicAdd(&cnt[dst[e]], 1);
}

__global__ void k_bsum(const int* __restrict__ counts, int* __restrict__ bsum) {
    int i = blockIdx.x * 256 + threadIdx.x;
    int v = (i < N_NODES) ? counts[i] : 0;
#pragma unroll
    for (int off = 32; off >= 1; off >>= 1) v += __shfl_xor(v, off, 64);
    __shared__ int ws[4];
    int lane = threadIdx.x & 63, wid = threadIdx.x >> 6;
    if (lane == 0) ws[wid] = v;
    __syncthreads();
    if (threadIdx.x == 0) bsum[blockIdx.x] = ws[0] + ws[1] + ws[2] + ws[3];
}

// self-scanning bfill: block b sums bsum[0..b) itself, then in-block exclusive scan
__global__ void k_bfill(const int* __restrict__ counts, const int* __restrict__ bsum,
                        int* __restrict__ row_ptr) {
    const int b = blockIdx.x, t = threadIdx.x;
    const int lane = t & 63, wid = t >> 6;
    __shared__ int wsum[4];
    __shared__ int ws[4];

    int bv = (t < b) ? bsum[t] : 0;
#pragma unroll
    for (int off = 32; off >= 1; off >>= 1) bv += __shfl_xor(bv, off, 64);
    if (lane == 0) wsum[wid] = bv;
    __syncthreads();
    const int boff = wsum[0] + wsum[1] + wsum[2] + wsum[3];

    int i = b * 256 + t;
    int v = (i < N_NODES) ? counts[i] : 0;
    int incl = v;
#pragma unroll
    for (int off = 1; off < 64; off <<= 1) {
        int u = __shfl_up(incl, off, 64);
        if (lane >= off) incl += u;
    }
    if (lane == 63) ws[wid] = incl;
    __syncthreads();
    int wo = 0;
#pragma unroll
    for (int j = 0; j < 4; ++j) if (j < wid) wo += ws[j];
    if (i < N_NODES) row_ptr[i] = boff + wo + incl - v;
    if (i == 0) row_ptr[N_NODES] = N_EDGES;
}

// consumes counts via atomicSub: pos = row_ptr[d+1] - remaining
__global__ void k_fill(const int* __restrict__ src, const int* __restrict__ dst,
                       const int* __restrict__ row_ptr, int* __restrict__ counts,
                       int* __restrict__ csr_src) {
    int e = blockIdx.x * 256 + threadIdx.x;
    if (e < N_EDGES) {
        int d = dst[e];
        int old = atomicSub(&counts[d], 1);
        csr_src[row_ptr[d + 1] - old] = src[e];
    }
}

// ---------------- prep: feat fp32->bf16 + 5 weights -> bf16 transposed + zero counts ----
#define FEAT_UNITS (N_NODES * F / 4)   // 1,600,000 float4 units
#define CNT_UNITS  ((N_NODES + 3) / 4) // 12,500 int4 units
__global__ void k_prep(const float* __restrict__ feat, u16* __restrict__ featb,
                       const float* __restrict__ Wq, const float* __restrict__ Wk,
                       const float* __restrict__ Wv, const float* __restrict__ W1,
                       const float* __restrict__ W2, u16* __restrict__ WT,
                       int* __restrict__ counts) {
    int idx = blockIdx.x * 256 + threadIdx.x;
    if (idx < FEAT_UNITS) {
        float4 v = reinterpret_cast<const float4*>(feat)[idx];
        uint2 p;
        p.x = pack2(v.x, v.y);
        p.y = pack2(v.z, v.w);
        reinterpret_cast<uint2*>(featb)[idx] = p;
        return;
    }
    int wi = idx - FEAT_UNITS;
    if (wi < 49152) {
        int mi = wi >> 14;
        int local = wi & 16383;
        const float* W = (mi == 0) ? Wq : ((mi == 1) ? Wk : Wv);
        int n = local >> 7, k = local & 127;
        WT[wi] = f2bf(W[(size_t)k * 128 + n]);
    } else if (wi < 114688) {
        int local = wi - 49152;
        int n = local >> 7, k = local & 127;
        WT[wi] = f2bf(W1[(size_t)k * 512 + n]);
    } else if (wi < 180224) {
        int local = wi - 114688;
        int n = local >> 9, k = local & 511;
        WT[wi] = f2bf(W2[(size_t)k * 128 + n]);
    } else if (wi < 180224 + CNT_UNITS) {
        reinterpret_cast<int4*>(counts)[wi - 180224] = make_int4(0, 0, 0, 0);
    }
}

// ---------------- MFMA GEMM: 128x128 tile, K-chunk 64 reg-dbuf, XOR-swizzled LDS ----------
template <int EPI>
__global__ __launch_bounds__(256) void k_mm(
    const u16* __restrict__ A, int lda,
    const u16* __restrict__ BT,
    void* __restrict__ Cv, int ldc,
    int K,
    const float* __restrict__ bias,
    const float* __restrict__ prelu,
    const u16* __restrict__ resid,
    const float* __restrict__ g,
    const float* __restrict__ bb)
{
    __shared__ u16 smem[17408];
    u16* sA = smem;                 // 128 rows x 64 u16 (swizzled)
    u16* sB = smem + 128 * 64;
    u16* sC = smem;                 // epilogue overlay

    const int t = threadIdx.x;
    const int w = t >> 6;
    const int lane = t & 63;
    const int ln = lane & 15, q4 = lane >> 4;
    const int row0 = blockIdx.x * 128;
    const int cb = blockIdx.y * 128;

    f32x4 acc[2][8];
#pragma unroll
    for (int mt = 0; mt < 2; ++mt)
#pragma unroll
        for (int nt = 0; nt < 8; ++nt)
            acc[mt][nt] = (f32x4){0.f, 0.f, 0.f, 0.f};

    uint4 pa[4], pb[4];
#define LOAD_A(kc)                                                             \
    {                                                                          \
        _Pragma("unroll") for (int i = 0; i < 4; ++i) {                        \
            int u = i * 256 + t, r = u >> 3, k8 = (u & 7) * 8;                 \
            int row = row0 + r;                                                \
            uint4 val = make_uint4(0, 0, 0, 0);                                \
            if (row < N_NODES)                                                 \
                val = *reinterpret_cast<const uint4*>(A + (size_t)row * lda + (kc) + k8); \
            pa[i] = val;                                                       \
        }                                                                      \
    }
#define LOAD_B(kc)                                                             \
    {                                                                          \
        _Pragma("unroll") for (int i = 0; i < 4; ++i) {                        \
            int u = i * 256 + t, r = u >> 3, k8 = (u & 7) * 8;                 \
            pb[i] = *reinterpret_cast<const uint4*>(BT + (size_t)(cb + r) * K + (kc) + k8); \
        }                                                                      \
    }

    LOAD_A(0);
    LOAD_B(0);

    for (int kc = 0; kc < K; kc += 64) {
#pragma unroll
        for (int i = 0; i < 4; ++i) {
            int u = i * 256 + t, r = u >> 3, gi = u & 7;
            int off = (r * 8 + (gi ^ (r & 7))) * 8;
            *reinterpret_cast<uint4*>(&sA[off]) = pa[i];
            *reinterpret_cast<uint4*>(&sB[off]) = pb[i];
        }
        __syncthreads();
        if (kc + 64 < K) {
            LOAD_A(kc + 64);
            LOAD_B(kc + 64);
        }
#pragma unroll
        for (int ks = 0; ks < 2; ++ks) {
            const int gsw = ks * 4 + q4;
            const int rA0 = w * 32 + ln;
            const int rA1 = rA0 + 16;
            bf16x8 a0 = *reinterpret_cast<const bf16x8*>(&sA[(rA0 * 8 + (gsw ^ (rA0 & 7))) * 8]);
            bf16x8 a1 = *reinterpret_cast<const bf16x8*>(&sA[(rA1 * 8 + (gsw ^ (rA1 & 7))) * 8]);
#pragma unroll
            for (int nt = 0; nt < 8; ++nt) {
                const int rB = nt * 16 + ln;
                bf16x8 b = *reinterpret_cast<const bf16x8*>(&sB[(rB * 8 + (gsw ^ (rB & 7))) * 8]);
                acc[0][nt] = __builtin_amdgcn_mfma_f32_16x16x32_bf16(a0, b, acc[0][nt], 0, 0, 0);
                acc[1][nt] = __builtin_amdgcn_mfma_f32_16x16x32_bf16(a1, b, acc[1][nt], 0, 0, 0);
            }
        }
        __syncthreads();
    }
#undef LOAD_A
#undef LOAD_B

    if (EPI == 0 || EPI == 1) {
        float bs[8], pr[8];
        if (EPI == 1) {
#pragma unroll
            for (int nt = 0; nt < 8; ++nt) {
                int col = cb + nt * 16 + ln;
                bs[nt] = bias[col];
                pr[nt] = prelu[col];
            }
        }
#pragma unroll
        for (int mt = 0; mt < 2; ++mt)
#pragma unroll
            for (int nt = 0; nt < 8; ++nt)
#pragma unroll
                for (int j = 0; j < 4; ++j) {
                    float x = acc[mt][nt][j];
                    if (EPI == 1) {
                        x += bs[nt];
                        x = (x >= 0.f) ? x : pr[nt] * x;
                    }
                    sC[(w * 32 + mt * 16 + q4 * 4 + j) * 136 + nt * 16 + ln] = f2bf(x);
                }
        __syncthreads();
        u16* C = (u16*)Cv;
#pragma unroll
        for (int i = 0; i < 8; ++i) {
            int u = i * 256 + t;
            int r = u >> 4, c8 = (u & 15) * 8;
            int row = row0 + r;
            if (row < N_NODES) {
                uint4 val = *reinterpret_cast<const uint4*>(&sC[r * 136 + c8]);
                *reinterpret_cast<uint4*>(&C[(size_t)row * ldc + cb + c8]) = val;
            }
        }
    } else {
        float* C = (float*)Cv;
        float bs[8], gv[8], bv[8];
#pragma unroll
        for (int nt = 0; nt < 8; ++nt) {
            int col = nt * 16 + ln;
            bs[nt] = bias[col];
            gv[nt] = g[col];
            bv[nt] = bb[col];
        }
#pragma unroll
        for (int mt = 0; mt < 2; ++mt)
#pragma unroll
            for (int j = 0; j < 4; ++j) {
                int row = row0 + w * 32 + mt * 16 + q4 * 4 + j;
                bool ok = row < N_NODES;
                float vals[8];
                float s = 0.f, ss = 0.f;
#pragma unroll
                for (int nt = 0; nt < 8; ++nt) {
                    float x = acc[mt][nt][j] + bs[nt];
                    if (ok) x += bf2f(resid[(size_t)row * 128 + nt * 16 + ln]);
                    vals[nt] = x;
                    s += x; ss += x * x;
                }
                s += __shfl_xor(s, 8, 16); ss += __shfl_xor(ss, 8, 16);
                s += __shfl_xor(s, 4, 16); ss += __shfl_xor(ss, 4, 16);
                s += __shfl_xor(s, 2, 16); ss += __shfl_xor(ss, 2, 16);
                s += __shfl_xor(s, 1, 16); ss += __shfl_xor(ss, 1, 16);
                float mu = s * (1.f / 128.f);
                float var = ss * (1.f / 128.f) - mu * mu;
                float rs = rsqrtf(var + 1e-5f);
                if (ok) {
#pragma unroll
                    for (int nt = 0; nt < 8; ++nt)
                        C[(size_t)row * 128 + nt * 16 + ln] =
                            (vals[nt] - mu) * rs * gv[nt] + bv[nt];
                }
            }
    }
}

// ---------------- attention: head-per-lane, 8 edges in flight per wave ----------------
// qkv per node (u32 view, 192 words): q 0..63, k 64..127, v 128..191.
// lane = es*8 + h: h = lane&7 (head), es = lane>>3 (edge slot). Lane owns all 16 dims
// of head h: q/acc in registers, k/v as 2x uint4 loads. No shuffles in the edge loop.
__global__ __launch_bounds__(256) void k_attn(
    const u32* __restrict__ Q32, const float* __restrict__ feat,
    const int* __restrict__ row_ptr, const int* __restrict__ csr_src,
    const float* __restrict__ g, const float* __restrict__ bb,
    u16* __restrict__ rstb)
{
    const int w = threadIdx.x >> 6;
    const int lane = threadIdx.x & 63;
    const int n = blockIdx.x * 4 + w;
    if (n >= N_NODES) return;
    const int h = lane & 7;
    const int es = lane >> 3;
    const float scale = 0.08838834764831845f;  // 1/sqrt(128)

    // q for head h -> 16 fp32 regs
    float qf[16];
    {
        uint4 qa = *reinterpret_cast<const uint4*>(&Q32[(size_t)n * 192 + h * 8]);
        uint4 qb = *reinterpret_cast<const uint4*>(&Q32[(size_t)n * 192 + h * 8 + 4]);
        qf[0] = blo(qa.x); qf[1] = bhi(qa.x); qf[2] = blo(qa.y); qf[3] = bhi(qa.y);
        qf[4] = blo(qa.z); qf[5] = bhi(qa.z); qf[6] = blo(qa.w); qf[7] = bhi(qa.w);
        qf[8] = blo(qb.x); qf[9] = bhi(qb.x); qf[10] = blo(qb.y); qf[11] = bhi(qb.y);
        qf[12] = blo(qb.z); qf[13] = bhi(qb.z); qf[14] = blo(qb.w); qf[15] = bhi(qb.w);
    }

    const int e0 = row_ptr[n], e1 = row_ptr[n + 1];
    float acc[16];
#pragma unroll
    for (int d = 0; d < 16; ++d) acc[d] = 0.f;
    float l = 0.f;

    for (int eb = e0; eb < e1; eb += 8) {
        int e = eb + es;
        bool valid = e < e1;
        int sn = csr_src[valid ? e : e1 - 1];
        const u32* base = &Q32[(size_t)sn * 192 + h * 8];
        uint4 k0 = *reinterpret_cast<const uint4*>(base + 64);
        uint4 k1 = *reinterpret_cast<const uint4*>(base + 68);
        uint4 v0 = *reinterpret_cast<const uint4*>(base + 128);
        uint4 v1 = *reinterpret_cast<const uint4*>(base + 132);

        float p0 = 0.f, p1 = 0.f, p2 = 0.f, p3 = 0.f;
        p0 = fmaf(blo(k0.x), qf[0], p0);  p1 = fmaf(bhi(k0.x), qf[1], p1);
        p2 = fmaf(blo(k0.y), qf[2], p2);  p3 = fmaf(bhi(k0.y), qf[3], p3);
        p0 = fmaf(blo(k0.z), qf[4], p0);  p1 = fmaf(bhi(k0.z), qf[5], p1);
        p2 = fmaf(blo(k0.w), qf[6], p2);  p3 = fmaf(bhi(k0.w), qf[7], p3);
        p0 = fmaf(blo(k1.x), qf[8], p0);  p1 = fmaf(bhi(k1.x), qf[9], p1);
        p2 = fmaf(blo(k1.y), qf[10], p2); p3 = fmaf(bhi(k1.y), qf[11], p3);
        p0 = fmaf(blo(k1.z), qf[12], p0); p1 = fmaf(bhi(k1.z), qf[13], p1);
        p2 = fmaf(blo(k1.w), qf[14], p2); p3 = fmaf(bhi(k1.w), qf[15], p3);
        float p = (p0 + p1) + (p2 + p3);

        float ea = valid ? __expf(p * scale) : 0.f;
        l += ea;
        acc[0]  = fmaf(ea, blo(v0.x), acc[0]);  acc[1]  = fmaf(ea, bhi(v0.x), acc[1]);
        acc[2]  = fmaf(ea, blo(v0.y), acc[2]);  acc[3]  = fmaf(ea, bhi(v0.y), acc[3]);
        acc[4]  = fmaf(ea, blo(v0.z), acc[4]);  acc[5]  = fmaf(ea, bhi(v0.z), acc[5]);
        acc[6]  = fmaf(ea, blo(v0.w), acc[6]);  acc[7]  = fmaf(ea, bhi(v0.w), acc[7]);
        acc[8]  = fmaf(ea, blo(v1.x), acc[8]);  acc[9]  = fmaf(ea, bhi(v1.x), acc[9]);
        acc[10] = fmaf(ea, blo(v1.y), acc[10]); acc[11] = fmaf(ea, bhi(v1.y), acc[11]);
        acc[12] = fmaf(ea, blo(v1.z), acc[12]); acc[13] = fmaf(ea, bhi(v1.z), acc[13]);
        acc[14] = fmaf(ea, blo(v1.w), acc[14]); acc[15] = fmaf(ea, bhi(v1.w), acc[15]);
    }

    // reduce across the 8 edge-slot groups (lane bits 3..5)
#pragma unroll
    for (int m = 8; m <= 32; m <<= 1) {
        l += __shfl_xor(l, m, 64);
#pragma unroll
        for (int d = 0; d < 16; ++d) acc[d] += __shfl_xor(acc[d], m, 64);
    }
    float inv = (l > 0.f) ? 1.f / l : 0.f;   // deg-0 node -> 0

    // residual + LN partials over this head's 16 dims
    float x[16];
    float s = 0.f, ss = 0.f;
    const float4* fp = reinterpret_cast<const float4*>(feat + (size_t)n * 128 + h * 16);
#pragma unroll
    for (int i = 0; i < 4; ++i) {
        float4 f4 = fp[i];
        float a0 = fmaf(acc[4 * i + 0], inv, f4.x);
        float a1 = fmaf(acc[4 * i + 1], inv, f4.y);
        float a2 = fmaf(acc[4 * i + 2], inv, f4.z);
        float a3 = fmaf(acc[4 * i + 3], inv, f4.w);
        x[4 * i + 0] = a0; x[4 * i + 1] = a1; x[4 * i + 2] = a2; x[4 * i + 3] = a3;
        s += (a0 + a1) + (a2 + a3);
        ss += (a0 * a0 + a1 * a1) + (a2 * a2 + a3 * a3);
    }
    // reduce across heads (lane bits 0..2)
#pragma unroll
    for (int m = 1; m <= 4; m <<= 1) {
        s += __shfl_xor(s, m, 64);
        ss += __shfl_xor(ss, m, 64);
    }
    float mu = s * (1.f / 128.f);
    float var = ss * (1.f / 128.f) - mu * mu;
    float rs = rsqrtf(var + 1e-5f);

    if (es == 0) {
        const float4* gp = reinterpret_cast<const float4*>(g + h * 16);
        const float4* bp = reinterpret_cast<const float4*>(bb + h * 16);
        uint4 o0, o1;
        u32 ww[8];
#pragma unroll
        for (int i = 0; i < 4; ++i) {
            float4 gv = gp[i], bv = bp[i];
            float y0 = (x[4 * i + 0] - mu) * rs * gv.x + bv.x;
            float y1 = (x[4 * i + 1] - mu) * rs * gv.y + bv.y;
            float y2 = (x[4 * i + 2] - mu) * rs * gv.z + bv.z;
            float y3 = (x[4 * i + 3] - mu) * rs * gv.w + bv.w;
            ww[2 * i] = pack2(y0, y1);
            ww[2 * i + 1] = pack2(y2, y3);
        }
        o0 = make_uint4(ww[0], ww[1], ww[2], ww[3]);
        o1 = make_uint4(ww[4], ww[5], ww[6], ww[7]);
        uint4* outp = reinterpret_cast<uint4*>(rstb + (size_t)n * 128 + h * 16);
        outp[0] = o0;
        outp[1] = o1;
    }
}

extern "C" void kernel_launch(void* const* d_in, const int* in_sizes, int n_in,
                              void* d_out, int out_size, void* d_ws, size_t ws_size,
                              hipStream_t stream)
{
    const float* feat = (const float*)d_in[0];
    const int* src    = (const int*)d_in[1];
    const int* dst    = (const int*)d_in[2];
    const float* Wq   = (const float*)d_in[3];
    const float* Wk   = (const float*)d_in[4];
    const float* Wv   = (const float*)d_in[5];
    const float* ln_g = (const float*)d_in[6];
    const float* ln_b = (const float*)d_in[7];
    const float* W1   = (const float*)d_in[8];
    const float* b1   = (const float*)d_in[9];
    const float* pa   = (const float*)d_in[10];
    const float* W2   = (const float*)d_in[11];
    const float* b2   = (const float*)d_in[12];

    u16* qkv   = (u16*)d_ws;                           // 50000*384
    u16* h     = qkv + (size_t)N_NODES * 384;          // 50000*512 (featb aliases front)
    u16* featb = h;                                    // 50000*128, dead before h written
    u16* rstb  = h + (size_t)N_NODES * 512;            // 50000*128
    u16* WT    = rstb + (size_t)N_NODES * 128;         // 180224
    u16* BqkvT = WT;
    u16* W1T   = WT + 49152;
    u16* W2T   = WT + 114688;
    int* counts  = (int*)(WT + 180224);
    int* row_ptr = counts + ((N_NODES + 3) & ~3);
    int* csr_src = row_ptr + N_NODES + 1;
    int* bsum    = csr_src + N_EDGES;

    k_prep<<<(FEAT_UNITS + 180224 + CNT_UNITS + 255) / 256, 256, 0, stream>>>(
        feat, featb, Wq, Wk, Wv, W1, W2, WT, counts);

    k_hist<<<(N_EDGES + 255) / 256, 256, 0, stream>>>(dst, counts);
    k_bsum<<<NB, 256, 0, stream>>>(counts, bsum);
    k_bfill<<<NB, 256, 0, stream>>>(counts, bsum, row_ptr);
    k_fill<<<(N_EDGES + 255) / 256, 256, 0, stream>>>(src, dst, row_ptr, counts, csr_src);

    const int MBK = (N_NODES + 127) / 128;   // 391

    dim3 gqkv(MBK, 3);
    k_mm<0><<<gqkv, 256, 0, stream>>>(featb, 128, BqkvT, qkv, 384, 128,
                                      nullptr, nullptr, nullptr, nullptr, nullptr);

    k_attn<<<(N_NODES + 3) / 4, 256, 0, stream>>>((const u32*)qkv, feat, row_ptr, csr_src,
                                                  ln_g, ln_b, rstb);

    dim3 gf1(MBK, 4);
    k_mm<1><<<gf1, 256, 0, stream>>>(rstb, 128, W1T, h, 512, 128,
                                     b1, pa, nullptr, nullptr, nullptr);

    dim3 gf2(MBK, 1);
    k_mm<2><<<gf2, 256, 0, stream>>>(h, 512, W2T, d_out, 128, 512,
                                     b2, nullptr, rstb, ln_g, ln_b);
}